// Round 4
// baseline (94.840 us; speedup 1.0000x reference)
//
#include <hip/hip_runtime.h>

// SHAPE = (16, 128, 4096, 3): rows = 2048, row_len = 12288 floats = 3072 float4
// pass1 grid = 4096 blocks:
//   blocks 0..2047    : per-row euclid sums over {out, gt1, gt2} vs target
//   blocks 2048..4095 : gt2_var partial sums of (-log v + v^2/8)
// R4: explicit depth-2 software pipeline with NAMED registers (no arrays) so the
// scheduler cannot sink loads to uses. Steady state: 16 float4 loads in flight
// per wave on the euclid path (counted vmcnt waits), vs ~4-6 in R3.
#define NROW    2048
#define ROW_V4  3072
#define NT      256

// accumulate squared diffs for one float4 triple against target
#define ACC12(T_,O_,A_,B_)                            \
  { float d;                                          \
    d = O_.x - T_.x; so = fmaf(d, d, so);             \
    d = O_.y - T_.y; so = fmaf(d, d, so);             \
    d = O_.z - T_.z; so = fmaf(d, d, so);             \
    d = O_.w - T_.w; so = fmaf(d, d, so);             \
    d = A_.x - T_.x; s1 = fmaf(d, d, s1);             \
    d = A_.y - T_.y; s1 = fmaf(d, d, s1);             \
    d = A_.z - T_.z; s1 = fmaf(d, d, s1);             \
    d = A_.w - T_.w; s1 = fmaf(d, d, s1);             \
    d = B_.x - T_.x; s2 = fmaf(d, d, s2);             \
    d = B_.y - T_.y; s2 = fmaf(d, d, s2);             \
    d = B_.z - T_.z; s2 = fmaf(d, d, s2);             \
    d = B_.w - T_.w; s2 = fmaf(d, d, s2); }

// load one group (2 iterations x 4 streams = 8 float4 loads)
#define LOADG(T0_,T1_,O0_,O1_,A0_,A1_,B0_,B1_, G_)    \
  { const int i0_ = tid + (2*(G_))*NT;                \
    const int i1_ = i0_ + NT;                         \
    T0_ = t4[i0_]; T1_ = t4[i1_];                     \
    O0_ = o4[i0_]; O1_ = o4[i1_];                     \
    A0_ = a4[i0_]; A1_ = a4[i1_];                     \
    B0_ = b4[i0_]; B1_ = b4[i1_]; }

#define VACC(V_)                                      \
  sb += fmaf(V_.x, V_.x * 0.125f, -__logf(V_.x));     \
  sb += fmaf(V_.y, V_.y * 0.125f, -__logf(V_.y));     \
  sb += fmaf(V_.z, V_.z * 0.125f, -__logf(V_.z));     \
  sb += fmaf(V_.w, V_.w * 0.125f, -__logf(V_.w));

#define VLOADG(V0_,V1_,V2_, G_)                       \
  { const int i0_ = tid + (3*(G_))*NT;                \
    V0_ = v4[i0_]; V1_ = v4[i0_+NT]; V2_ = v4[i0_+2*NT]; }

__global__ __launch_bounds__(NT) void pass1(
    const float* __restrict__ outp,
    const float* __restrict__ targp,
    const float* __restrict__ g1p,
    const float* __restrict__ g2p,
    const float* __restrict__ gvp,
    float4* __restrict__ rowbuf,     // [2048] {sqrt(so), sqrt(s1), sqrt(s2), sq-combo}
    float*  __restrict__ varbuf)     // [2048] partial sums of (-log v + v^2/8)
{
    __shared__ float red[4][3];
    const int bid  = blockIdx.x;
    const int tid  = threadIdx.x;
    const int wid  = tid >> 6;
    const int lane = tid & 63;

    if (bid < NROW) {
        const size_t base = (size_t)bid * ROW_V4;
        const float4* __restrict__ t4 = (const float4*)targp + base;
        const float4* __restrict__ o4 = (const float4*)outp  + base;
        const float4* __restrict__ a4 = (const float4*)g1p   + base;
        const float4* __restrict__ b4 = (const float4*)g2p   + base;

        float so = 0.f, s1 = 0.f, s2 = 0.f;

        // two ping-pong register groups, depth-2 pipeline over 6 groups
        float4 Ta0,Ta1,Oa0,Oa1,Aa0,Aa1,Ba0,Ba1;
        float4 Tb0,Tb1,Ob0,Ob1,Ab0,Ab1,Bb0,Bb1;

        LOADG(Ta0,Ta1,Oa0,Oa1,Aa0,Aa1,Ba0,Ba1, 0)
        LOADG(Tb0,Tb1,Ob0,Ob1,Ab0,Ab1,Bb0,Bb1, 1)
        ACC12(Ta0,Oa0,Aa0,Ba0) ACC12(Ta1,Oa1,Aa1,Ba1)
        LOADG(Ta0,Ta1,Oa0,Oa1,Aa0,Aa1,Ba0,Ba1, 2)
        ACC12(Tb0,Ob0,Ab0,Bb0) ACC12(Tb1,Ob1,Ab1,Bb1)
        LOADG(Tb0,Tb1,Ob0,Ob1,Ab0,Ab1,Bb0,Bb1, 3)
        ACC12(Ta0,Oa0,Aa0,Ba0) ACC12(Ta1,Oa1,Aa1,Ba1)
        LOADG(Ta0,Ta1,Oa0,Oa1,Aa0,Aa1,Ba0,Ba1, 4)
        ACC12(Tb0,Ob0,Ab0,Bb0) ACC12(Tb1,Ob1,Ab1,Bb1)
        LOADG(Tb0,Tb1,Ob0,Ob1,Ab0,Ab1,Bb0,Bb1, 5)
        ACC12(Ta0,Oa0,Aa0,Ba0) ACC12(Ta1,Oa1,Aa1,Ba1)
        ACC12(Tb0,Ob0,Ab0,Bb0) ACC12(Tb1,Ob1,Ab1,Bb1)

        #pragma unroll
        for (int off = 32; off; off >>= 1) {
            so += __shfl_down(so, off);
            s1 += __shfl_down(s1, off);
            s2 += __shfl_down(s2, off);
        }
        if (lane == 0) { red[wid][0] = so; red[wid][1] = s1; red[wid][2] = s2; }
        __syncthreads();
        if (tid == 0) {
            float r0 = 0.f, r1 = 0.f, r2 = 0.f;
            #pragma unroll
            for (int w = 0; w < 4; ++w) { r0 += red[w][0]; r1 += red[w][1]; r2 += red[w][2]; }
            float4 r;
            r.x = sqrtf(r0);
            r.y = sqrtf(r1);
            r.z = sqrtf(r2);
            r.w = fmaf(0.125f, r0, fmaf(0.025f, r1, 0.025f * r2));  // KL sq-diff combo
            rowbuf[bid] = r;
        }
    } else {
        const size_t base = (size_t)(bid - NROW) * ROW_V4;
        const float4* __restrict__ v4 = (const float4*)gvp + base;
        float sb = 0.f;

        float4 Va0, Va1, Va2, Vb0, Vb1, Vb2;
        VLOADG(Va0, Va1, Va2, 0)
        VLOADG(Vb0, Vb1, Vb2, 1)
        VACC(Va0) VACC(Va1) VACC(Va2)
        VLOADG(Va0, Va1, Va2, 2)
        VACC(Vb0) VACC(Vb1) VACC(Vb2)
        VLOADG(Vb0, Vb1, Vb2, 3)
        VACC(Va0) VACC(Va1) VACC(Va2)
        VACC(Vb0) VACC(Vb1) VACC(Vb2)

        #pragma unroll
        for (int off = 32; off; off >>= 1) sb += __shfl_down(sb, off);
        if (lane == 0) red[wid][0] = sb;
        __syncthreads();
        if (tid == 0)
            varbuf[bid - NROW] = red[0][0] + red[1][0] + red[2][0] + red[3][0];
    }
}

// Deterministic final reduction + scalar formula (single block).
__global__ __launch_bounds__(256) void final_kernel(
    const float4* __restrict__ rowbuf,
    const float*  __restrict__ varbuf,
    const float*  __restrict__ gt0p,
    const float*  __restrict__ legp,
    const float*  __restrict__ ldynp,
    float* __restrict__ resp)
{
    float a0 = 0.f, a1 = 0.f, a2 = 0.f, a3 = 0.f, sb = 0.f;
    for (int i = threadIdx.x; i < NROW; i += 256) {
        const float4 r = rowbuf[i];
        a0 += r.x; a1 += r.y; a2 += r.z; a3 += r.w;
        sb += varbuf[i];
    }
    #pragma unroll
    for (int off = 32; off; off >>= 1) {
        a0 += __shfl_down(a0, off);
        a1 += __shfl_down(a1, off);
        a2 += __shfl_down(a2, off);
        a3 += __shfl_down(a3, off);
        sb += __shfl_down(sb, off);
    }
    __shared__ float red[4][5];
    const int wid  = threadIdx.x >> 6;
    const int lane = threadIdx.x & 63;
    if (lane == 0) {
        red[wid][0] = a0; red[wid][1] = a1; red[wid][2] = a2;
        red[wid][3] = a3; red[wid][4] = sb;
    }
    __syncthreads();
    if (threadIdx.x == 0) {
        float r0 = 0.f, r1 = 0.f, r2 = 0.f, r3 = 0.f, rb = 0.f;
        #pragma unroll
        for (int w = 0; w < 4; ++w) {
            r0 += red[w][0]; r1 += red[w][1]; r2 += red[w][2];
            r3 += red[w][3]; rb += red[w][4];
        }
        const float Eo = r0 * (1.f / 128.f);
        const float E1 = r1 * (1.f / 128.f);
        const float E2 = r2 * (1.f / 128.f);
        // kl = 1.4*(SB + N*(ln2 - 0.5)) + (SO + 0.2*S1 + 0.2*S2)/8
        const float kl = 1.4f * (rb + 25165824.f * (0.69314718056f - 0.5f)) + r3;

        const float l_dyn    = ldynp[0];
        const float leg_term = 0.01f * 0.2f * l_dyn * legp[0];
        const float outloss  = Eo + leg_term;
        const float gt_loss  = 0.1f * E1 + 0.2f * E2;
        const float reg      = gt0p[0] * 0.01f * l_dyn;

        resp[0] = outloss + gt_loss + reg + kl / (1.2f * (Eo + gt_loss));
    }
}

extern "C" void kernel_launch(void* const* d_in, const int* in_sizes, int n_in,
                              void* d_out, int out_size, void* d_ws, size_t ws_size,
                              hipStream_t stream) {
    const float* outp  = (const float*)d_in[0];
    const float* targp = (const float*)d_in[1];
    const float* gt0p  = (const float*)d_in[2];
    const float* g1p   = (const float*)d_in[3];
    const float* g2p   = (const float*)d_in[4];
    const float* gvp   = (const float*)d_in[5];
    const float* legp  = (const float*)d_in[6];
    const float* ldynp = (const float*)d_in[7];

    float4* rowbuf = (float4*)d_ws;                 // 2048 * 16 B
    float*  varbuf = (float*)(rowbuf + NROW);       // 2048 * 4 B
    float*  resp   = (float*)d_out;

    pass1<<<2 * NROW, NT, 0, stream>>>(outp, targp, g1p, g2p, gvp, rowbuf, varbuf);
    final_kernel<<<1, 256, 0, stream>>>(rowbuf, varbuf, gt0p, legp, ldynp, resp);
}

// Round 5
// 94.143 us; speedup vs baseline: 1.0074x; 1.0074x over previous
//
#include <hip/hip_runtime.h>

// SHAPE = (16, 128, 4096, 3): rows = 2048, row_len = 12288 floats = 3072 float4.
// R5: uniform 48KB work units to fix the occupancy/imbalance problem seen in
// rocprof (Occupancy ~48%, both pipes idle; euclid blocks read 192KB vs var 48KB).
//   blocks 0..8191     : euclid QUARTER-row (row r = b>>2, quarter q = b&3),
//                        4 streams x 12KB, partial {so,s1,s2} -> eucbuf[b]
//   blocks 8192..10239 : var FULL row (1 stream x 48KB) -> varbuf[b-8192]
// final_kernel re-forms per-row sums from the 4 quarters BEFORE sqrt.
#define NROW    2048
#define ROW_V4  3072
#define QRT_V4  768            // float4 per quarter-row
#define NT      256
#define NEB     8192           // euclid blocks
#define NVB     2048           // var blocks

__global__ __launch_bounds__(NT) void pass1(
    const float* __restrict__ outp,
    const float* __restrict__ targp,
    const float* __restrict__ g1p,
    const float* __restrict__ g2p,
    const float* __restrict__ gvp,
    float4* __restrict__ eucbuf,     // [8192] {so, s1, s2, 0} per quarter-row
    float*  __restrict__ varbuf)     // [2048] per-row sums of (-log v + v^2/8)
{
    __shared__ float red[4][3];
    const int bid  = blockIdx.x;
    const int tid  = threadIdx.x;
    const int wid  = tid >> 6;
    const int lane = tid & 63;

    if (bid < NEB) {
        const int r = bid >> 2;
        const int q = bid & 3;
        const size_t base = (size_t)r * ROW_V4 + (size_t)q * QRT_V4;
        const float4* __restrict__ t4 = (const float4*)targp + base;
        const float4* __restrict__ o4 = (const float4*)outp  + base;
        const float4* __restrict__ a4 = (const float4*)g1p   + base;
        const float4* __restrict__ b4 = (const float4*)g2p   + base;

        float so = 0.f, s1 = 0.f, s2 = 0.f;
        #pragma unroll
        for (int k = 0; k < 3; ++k) {
            const int i = tid + k * NT;
            const float4 t = t4[i];
            const float4 o = o4[i];
            const float4 a = a4[i];
            const float4 b = b4[i];
            float d;
            d = o.x - t.x; so = fmaf(d, d, so);
            d = o.y - t.y; so = fmaf(d, d, so);
            d = o.z - t.z; so = fmaf(d, d, so);
            d = o.w - t.w; so = fmaf(d, d, so);
            d = a.x - t.x; s1 = fmaf(d, d, s1);
            d = a.y - t.y; s1 = fmaf(d, d, s1);
            d = a.z - t.z; s1 = fmaf(d, d, s1);
            d = a.w - t.w; s1 = fmaf(d, d, s1);
            d = b.x - t.x; s2 = fmaf(d, d, s2);
            d = b.y - t.y; s2 = fmaf(d, d, s2);
            d = b.z - t.z; s2 = fmaf(d, d, s2);
            d = b.w - t.w; s2 = fmaf(d, d, s2);
        }
        #pragma unroll
        for (int off = 32; off; off >>= 1) {
            so += __shfl_down(so, off);
            s1 += __shfl_down(s1, off);
            s2 += __shfl_down(s2, off);
        }
        if (lane == 0) { red[wid][0] = so; red[wid][1] = s1; red[wid][2] = s2; }
        __syncthreads();
        if (tid == 0) {
            float r0 = 0.f, r1 = 0.f, r2 = 0.f;
            #pragma unroll
            for (int w = 0; w < 4; ++w) { r0 += red[w][0]; r1 += red[w][1]; r2 += red[w][2]; }
            eucbuf[bid] = make_float4(r0, r1, r2, 0.f);
        }
    } else {
        const int rv = bid - NEB;
        const size_t base = (size_t)rv * ROW_V4;
        const float4* __restrict__ v4 = (const float4*)gvp + base;
        float sb = 0.f;
        #pragma unroll
        for (int k = 0; k < 12; ++k) {
            const float4 v = v4[tid + k * NT];
            sb += fmaf(v.x, v.x * 0.125f, -__logf(v.x));
            sb += fmaf(v.y, v.y * 0.125f, -__logf(v.y));
            sb += fmaf(v.z, v.z * 0.125f, -__logf(v.z));
            sb += fmaf(v.w, v.w * 0.125f, -__logf(v.w));
        }
        #pragma unroll
        for (int off = 32; off; off >>= 1) sb += __shfl_down(sb, off);
        if (lane == 0) red[wid][0] = sb;
        __syncthreads();
        if (tid == 0)
            varbuf[rv] = red[0][0] + red[1][0] + red[2][0] + red[3][0];
    }
}

// Single block, 1024 threads. Re-form per-row sums (4 quarters), sqrt, and the
// final scalar formula. Fully deterministic (fixed summation order per thread,
// fixed tree across waves).
__global__ __launch_bounds__(1024) void final_kernel(
    const float4* __restrict__ eucbuf,
    const float*  __restrict__ varbuf,
    const float*  __restrict__ gt0p,
    const float*  __restrict__ legp,
    const float*  __restrict__ ldynp,
    float* __restrict__ resp)
{
    const int tid = threadIdx.x;
    float A0 = 0.f, A1 = 0.f, A2 = 0.f, K = 0.f, SB = 0.f;

    // 2048 rows over 1024 threads: rows tid and tid+1024
    #pragma unroll
    for (int h = 0; h < 2; ++h) {
        const int r = tid + h * 1024;
        float so = 0.f, s1 = 0.f, s2 = 0.f;
        #pragma unroll
        for (int q = 0; q < 4; ++q) {
            const float4 e = eucbuf[4 * r + q];
            so += e.x; s1 += e.y; s2 += e.z;
        }
        A0 += sqrtf(so);
        A1 += sqrtf(s1);
        A2 += sqrtf(s2);
        K  += fmaf(0.125f, so, fmaf(0.025f, s1, 0.025f * s2));
        SB += varbuf[r];
    }

    #pragma unroll
    for (int off = 32; off; off >>= 1) {
        A0 += __shfl_down(A0, off);
        A1 += __shfl_down(A1, off);
        A2 += __shfl_down(A2, off);
        K  += __shfl_down(K,  off);
        SB += __shfl_down(SB, off);
    }
    __shared__ float red[16][5];
    const int wid  = tid >> 6;
    const int lane = tid & 63;
    if (lane == 0) {
        red[wid][0] = A0; red[wid][1] = A1; red[wid][2] = A2;
        red[wid][3] = K;  red[wid][4] = SB;
    }
    __syncthreads();
    if (tid == 0) {
        float r0 = 0.f, r1 = 0.f, r2 = 0.f, r3 = 0.f, rb = 0.f;
        #pragma unroll
        for (int w = 0; w < 16; ++w) {
            r0 += red[w][0]; r1 += red[w][1]; r2 += red[w][2];
            r3 += red[w][3]; rb += red[w][4];
        }
        const float Eo = r0 * (1.f / 128.f);
        const float E1 = r1 * (1.f / 128.f);
        const float E2 = r2 * (1.f / 128.f);
        // kl = 1.4*(SB + N*(ln2 - 0.5)) + (SO + 0.2*S1 + 0.2*S2)/8
        const float kl = 1.4f * (rb + 25165824.f * (0.69314718056f - 0.5f)) + r3;

        const float l_dyn    = ldynp[0];
        const float leg_term = 0.01f * 0.2f * l_dyn * legp[0];
        const float outloss  = Eo + leg_term;
        const float gt_loss  = 0.1f * E1 + 0.2f * E2;
        const float reg      = gt0p[0] * 0.01f * l_dyn;

        resp[0] = outloss + gt_loss + reg + kl / (1.2f * (Eo + gt_loss));
    }
}

extern "C" void kernel_launch(void* const* d_in, const int* in_sizes, int n_in,
                              void* d_out, int out_size, void* d_ws, size_t ws_size,
                              hipStream_t stream) {
    const float* outp  = (const float*)d_in[0];
    const float* targp = (const float*)d_in[1];
    const float* gt0p  = (const float*)d_in[2];
    const float* g1p   = (const float*)d_in[3];
    const float* g2p   = (const float*)d_in[4];
    const float* gvp   = (const float*)d_in[5];
    const float* legp  = (const float*)d_in[6];
    const float* ldynp = (const float*)d_in[7];

    float4* eucbuf = (float4*)d_ws;                 // 8192 * 16 B = 128 KiB
    float*  varbuf = (float*)(eucbuf + NEB);        // 2048 * 4 B  =   8 KiB
    float*  resp   = (float*)d_out;

    pass1<<<NEB + NVB, NT, 0, stream>>>(outp, targp, g1p, g2p, gvp, eucbuf, varbuf);
    final_kernel<<<1, 1024, 0, stream>>>(eucbuf, varbuf, gt0p, legp, ldynp, resp);
}